// Round 15
// baseline (55.248 us; speedup 1.0000x reference)
//
#include <hip/hip_runtime.h>

#define HH 128
#define WW 128
#define PP (HH * WW)     // 16384
#define NBINS 32
#define KK 5
#define PADK 2
#define EPSF 1e-5f
#define CH 8192          // events per scatter block
#define SBT 512          // scatter block threads
#define EPT 16           // events per thread (CH/SBT)
#define SPLITS 8         // conv partial splits per row
#define FSPLIT 4         // finalize splits per row
#define CPX (PP / SPLITS)   // 2048 pixels per conv block
#define FCPX (PP / FSPLIT)  // 4096 pixels per finalize block
#define SLOTC 384        // u16 entries per (block,bin) slot; mean 256, +8 sigma
#define SENT 0x4000u     // sentinel pixel id (== PP); hist slot 8192 is dead

typedef float vfloat4 __attribute__((ext_vector_type(4)));

__device__ __forceinline__ float wave_sum(float v) {
#pragma unroll
    for (int off = 32; off > 0; off >>= 1) v += __shfl_down(v, off, 64);
    return v;
}

// --------------------------------------------- phase 1: bucket the events
// Single-pass LDS bucketing; 512-thread blocks (4 resident/CU = 32 waves/CU,
// vs 24 with 256-thread blocks at the same 24 KB LDS). Bin runs padded to
// 8-entry boundaries with sentinels so hist is guard-free. Extra block =
// param sums.
__global__ __launch_bounds__(SBT) void bucket_scatter(
    const float4* __restrict__ ev, int N, int bpb, int nBlk,
    unsigned short* __restrict__ buckets, unsigned short* __restrict__ lens,
    const float* __restrict__ pw, const float* __restrict__ pb,
    float* __restrict__ psums) {
    int wave = threadIdx.x >> 6, lane = threadIdx.x & 63;

    if ((int)blockIdx.x == nBlk) {      // ---- param sums side-block
        __shared__ float pr[8][5];
        float s0 = 0, s1 = 0, s2 = 0, s3 = 0, s4 = 0;
        for (int i = threadIdx.x; i < PP / 4; i += SBT) {
            float4 w = ((const float4*)pw)[i];
            float4 b4 = ((const float4*)pb)[i];
            s0 += w.x + w.y + w.z + w.w;
            s1 += w.x * w.x + w.y * w.y + w.z * w.z + w.w * w.w;
            s2 += b4.x + b4.y + b4.z + b4.w;
            s3 += b4.x * b4.x + b4.y * b4.y + b4.z * b4.z + b4.w * b4.w;
            s4 += w.x * b4.x + w.y * b4.y + w.z * b4.z + w.w * b4.w;
        }
        float acc[5] = {s0, s1, s2, s3, s4};
#pragma unroll
        for (int q = 0; q < 5; ++q) {
            float v = wave_sum(acc[q]);
            if (lane == 0) pr[wave][q] = v;
        }
        __syncthreads();
        if (threadIdx.x < 5) {
            float t = 0.f;
#pragma unroll
            for (int w = 0; w < 8; ++w) t += pr[w][threadIdx.x];
            psums[threadIdx.x] = t;
        }
        return;
    }

    __shared__ unsigned int cur[NBINS];
    __shared__ unsigned short sorted[NBINS * SLOTC];   // 24 KB

    int b = blockIdx.x / bpb;
    int j = blockIdx.x - b * bpb;
    int start = j * CH;
    int nev = min(CH, N - start);
    const float4* base = ev + (size_t)b * N + start;

    if (threadIdx.x < NBINS) cur[threadIdx.x] = 0;
    __syncthreads();

#pragma unroll
    for (int k = 0; k < EPT; k++) {
        int e = threadIdx.x + k * SBT;
        if (e < nev) {
            float4 q = base[e];
            int x = min(max((int)q.x, 0), HH - 1);
            int y = min(max((int)q.y, 0), WW - 1);
            float t = fminf(fmaxf(q.z, 0.0f), 1.0f);
            int bin = min((int)(t * (float)NBINS), NBINS - 1);
            unsigned int pos = atomicAdd(&cur[bin], 1u);
            if (pos < SLOTC) sorted[bin * SLOTC + pos] = (unsigned short)(x * WW + y);
        }
    }
    __syncthreads();

    // pad each bin run to an 8-entry boundary with sentinels; store padded len
    if (threadIdx.x < NBINS) {
        unsigned int len = min(cur[threadIdx.x], (unsigned int)SLOTC);
        unsigned int plen = (len + 7u) & ~7u;          // <= SLOTC (384 % 8 == 0)
        for (unsigned int i = len; i < plen; ++i)
            sorted[threadIdx.x * SLOTC + i] = (unsigned short)SENT;
        lens[(size_t)blockIdx.x * NBINS + threadIdx.x] = (unsigned short)plen;
        cur[threadIdx.x] = plen;
    }
    __syncthreads();

    // copy-out: wave w owns 4 bins; u32 writes of the padded run
    for (int i = 0; i < NBINS / 8; ++i) {
        int bin = wave * (NBINS / 8) + i;
        unsigned int nw = cur[bin] >> 1;
        unsigned int* dst = (unsigned int*)(buckets +
                            ((size_t)blockIdx.x * NBINS + bin) * SLOTC);
        const unsigned int* src = (const unsigned int*)(sorted + bin * SLOTC);
        for (unsigned int w = lane; w < nw; w += 64) dst[w] = src[w];
    }
}

// ------------------------- phase 2: per-bucket histogram (packed 16-bit)
// one block per (b,bin); guard-free uint4 slot walk, 32 KB LDS + dead slot.
__global__ __launch_bounds__(1024) void bucket_hist(
    const unsigned short* __restrict__ buckets,
    const unsigned short* __restrict__ lens, int bpb,
    unsigned short* __restrict__ counts) {
    __shared__ unsigned int hist[PP / 2 + 1];   // +1: sentinel slot (dead)
    int b = blockIdx.x >> 5;
    int bin = blockIdx.x & (NBINS - 1);
    int wave = threadIdx.x >> 6, lane = threadIdx.x & 63;

    for (int i = threadIdx.x; i < PP / 2 + 1; i += 1024) hist[i] = 0;
    __syncthreads();

    for (int j = wave; j < bpb; j += 16) {
        size_t slot = (size_t)(b * bpb + j) * NBINS + bin;
        int plen = lens[slot];                   // multiple of 8
        const uint4* src = (const uint4*)(buckets + slot * SLOTC);
        int nq = plen >> 3;
        for (int w = lane; w < nq; w += 64) {
            uint4 v = src[w];
#pragma unroll
            for (int m = 0; m < 4; ++m) {
                unsigned int pair = (&v.x)[m];
                unsigned int p0 = pair & 0xFFFFu, p1 = pair >> 16;
                atomicAdd(&hist[p0 >> 1], 1u << ((p0 & 1u) << 4));
                atomicAdd(&hist[p1 >> 1], 1u << ((p1 & 1u) << 4));
            }
        }
    }
    __syncthreads();

    unsigned int* dst = (unsigned int*)(counts + (size_t)blockIdx.x * PP);
    for (int i = threadIdx.x; i < PP / 2; i += 1024) dst[i] = hist[i];
}

// ----------------------- phase 3: conv over bins -> 6 partial sums per row
__global__ __launch_bounds__(256) void conv_partials(
    const unsigned short* __restrict__ counts, const float* __restrict__ gk,
    const float* __restrict__ pw, const float* __restrict__ pb,
    float* __restrict__ partials) {
    __shared__ float red[4][8];
    int row = blockIdx.x >> 3;          // / SPLITS
    int split = blockIdx.x & (SPLITS - 1);
    int bin = row & (NBINS - 1);
    const unsigned short* base = counts + (size_t)row * PP;
    float g0 = gk[0], g1 = gk[1], g2 = gk[2], g3 = gk[3], g4 = gk[4];

    float a0 = 0, a1 = 0, a2 = 0, a3 = 0, a4 = 0, a5 = 0;

#pragma unroll
    for (int it = 0; it < CPX / (256 * 4); ++it) {
        int p = split * CPX + (it * 256 + threadIdx.x) * 4;
        float4 c[KK];
#pragma unroll
        for (int k = 0; k < KK; ++k) {
            int bb = bin + k - PADK;
            if (bb >= 0 && bb < NBINS) {
                uint2 w = *(const uint2*)(base + (ptrdiff_t)(k - PADK) * PP + p);
                c[k] = make_float4((float)(w.x & 0xFFFFu), (float)(w.x >> 16),
                                   (float)(w.y & 0xFFFFu), (float)(w.y >> 16));
            } else {
                c[k] = make_float4(0.f, 0.f, 0.f, 0.f);
            }
        }
        float4 pw4 = *(const float4*)(pw + p);
        float4 pb4 = *(const float4*)(pb + p);

        float s0 = g0*c[0].x + g1*c[1].x + g2*c[2].x + g3*c[3].x + g4*c[4].x;
        float s1 = g0*c[0].y + g1*c[1].y + g2*c[2].y + g3*c[3].y + g4*c[4].y;
        float s2 = g0*c[0].z + g1*c[1].z + g2*c[2].z + g3*c[3].z + g4*c[4].z;
        float s3 = g0*c[0].w + g1*c[1].w + g2*c[2].w + g3*c[3].w + g4*c[4].w;

        float sv[4] = {s0, s1, s2, s3};
        float wv[4] = {pw4.x, pw4.y, pw4.z, pw4.w};
        float bv[4] = {pb4.x, pb4.y, pb4.z, pb4.w};
#pragma unroll
        for (int jj = 0; jj < 4; ++jj) {
            float s = sv[jj], w = wv[jj], bb = bv[jj];
            float sw = s * w;
            a0 += s;
            a1 += s * s;
            a2 += sw;
            a3 += sw * w;
            a4 += sw * sw;
            a5 += sw * bb;
        }
    }

    float acc[6] = {a0, a1, a2, a3, a4, a5};
    int wave = threadIdx.x >> 6, lane = threadIdx.x & 63;
#pragma unroll
    for (int q = 0; q < 6; ++q) {
        float w = wave_sum(acc[q]);
        if (lane == 0) red[wave][q] = w;
    }
    __syncthreads();
    if (threadIdx.x < 6) {
        float s = red[0][threadIdx.x] + red[1][threadIdx.x] +
                  red[2][threadIdx.x] + red[3][threadIdx.x];
        partials[(size_t)blockIdx.x * 6 + threadIdx.x] = s;
    }
}

// ------------- phase 4: recompute stats in-block + conv + both norms + out
__global__ __launch_bounds__(256) void finalize_conv(
    const unsigned short* __restrict__ counts, const float* __restrict__ gk,
    const float* __restrict__ pw, const float* __restrict__ pb,
    const float* __restrict__ gw, const float* __restrict__ gb,
    const float* __restrict__ partials, const float* __restrict__ psums,
    float* __restrict__ out) {
    __shared__ float ys[NBINS], ys2[NBINS];
    __shared__ float sstat[4];   // mu, rstd, bmu, brstd
    int row = blockIdx.x >> 2;          // / FSPLIT
    int split = blockIdx.x & (FSPLIT - 1);
    int bin = row & (NBINS - 1);
    int t = threadIdx.x;

    if (t < NBINS) {
        float spw = psums[0], spw2 = psums[1], spb = psums[2],
              spb2 = psums[3], spwpb = psums[4];
        int r = (row & ~(NBINS - 1)) + t;       // row t of this batch
        float S0 = 0, S1 = 0, S2 = 0, S3 = 0, S4 = 0, S5 = 0;
        for (int sp = 0; sp < SPLITS; ++sp) {
            const float* pp = partials + ((size_t)r * SPLITS + sp) * 6;
            S0 += pp[0]; S1 += pp[1]; S2 += pp[2];
            S3 += pp[3]; S4 += pp[4]; S5 += pp[5];
        }
        const float invP = 1.0f / (float)PP;
        float mu = S0 * invP;
        float var = S1 * invP - mu * mu;
        float rstd = rsqrtf(var + EPSF);
        ys[t]  = rstd * (S2 - mu * spw) + spb;
        ys2[t] = rstd * rstd * (S4 - 2.f * mu * S3 + mu * mu * spw2)
               + 2.f * rstd * (S5 - mu * spwpb) + spb2;
        if (t == bin) { sstat[0] = mu; sstat[1] = rstd; }
    }
    __syncthreads();
    if (t == 0) {
        float s = 0.f, q = 0.f;
        for (int r = 0; r < NBINS; ++r) { s += ys[r]; q += ys2[r]; }
        const float inv = 1.0f / (float)(NBINS * PP);
        float bmu = s * inv;
        float bvar = q * inv - bmu * bmu;
        sstat[2] = bmu;
        sstat[3] = rsqrtf(bvar + EPSF);
    }
    __syncthreads();
    float rmu = sstat[0], rrstd = sstat[1], bmu = sstat[2], brstd = sstat[3];

    const unsigned short* base = counts + (size_t)row * PP;
    float g0 = gk[0], g1 = gk[1], g2 = gk[2], g3 = gk[3], g4 = gk[4];

#pragma unroll
    for (int it = 0; it < FCPX / (256 * 4); ++it) {
        int p = split * FCPX + (it * 256 + threadIdx.x) * 4;
        float4 c[KK];
#pragma unroll
        for (int k = 0; k < KK; ++k) {
            int bb = bin + k - PADK;
            if (bb >= 0 && bb < NBINS) {
                uint2 w = *(const uint2*)(base + (ptrdiff_t)(k - PADK) * PP + p);
                c[k] = make_float4((float)(w.x & 0xFFFFu), (float)(w.x >> 16),
                                   (float)(w.y & 0xFFFFu), (float)(w.y >> 16));
            } else {
                c[k] = make_float4(0.f, 0.f, 0.f, 0.f);
            }
        }
        float4 pw4 = *(const float4*)(pw + p);
        float4 pb4 = *(const float4*)(pb + p);
        int rp = bin * PP + p;
        float4 w4 = *(const float4*)(gw + rp);
        float4 b4 = *(const float4*)(gb + rp);

        float s0 = g0*c[0].x + g1*c[1].x + g2*c[2].x + g3*c[3].x + g4*c[4].x;
        float s1 = g0*c[0].y + g1*c[1].y + g2*c[2].y + g3*c[3].y + g4*c[4].y;
        float s2 = g0*c[0].z + g1*c[1].z + g2*c[2].z + g3*c[3].z + g4*c[4].z;
        float s3 = g0*c[0].w + g1*c[1].w + g2*c[2].w + g3*c[3].w + g4*c[4].w;

        vfloat4 r;
        r.x = (((s0 - rmu) * rrstd) * pw4.x + pb4.x - bmu) * brstd * w4.x + b4.x;
        r.y = (((s1 - rmu) * rrstd) * pw4.y + pb4.y - bmu) * brstd * w4.y + b4.y;
        r.z = (((s2 - rmu) * rrstd) * pw4.z + pb4.z - bmu) * brstd * w4.z + b4.z;
        r.w = (((s3 - rmu) * rrstd) * pw4.w + pb4.w - bmu) * brstd * w4.w + b4.w;
        __builtin_nontemporal_store(r, (vfloat4*)(out + (size_t)row * PP + p));
    }
}

extern "C" void kernel_launch(void* const* d_in, const int* in_sizes, int n_in,
                              void* d_out, int out_size, void* d_ws, size_t ws_size,
                              hipStream_t stream) {
    const float* events = (const float*)d_in[0];
    const float* gk     = (const float*)d_in[2];
    const float* pw     = (const float*)d_in[3];
    const float* pb     = (const float*)d_in[4];
    const float* gw     = (const float*)d_in[5];
    const float* gb     = (const float*)d_in[6];
    float* out = (float*)d_out;

    int total_events = in_sizes[0] / 4;
    int B = out_size / (NBINS * PP);           // 8
    int N = total_events / B;                  // 1,000,000
    int n_rows = B * NBINS;                    // 256
    int bpb = (N + CH - 1) / CH;               // 123
    int nBlk = B * bpb;                        // 984

    size_t count_bytes = (size_t)out_size * sizeof(unsigned short);   // 8 MB
    char* wp = (char*)d_ws;
    unsigned short* counts = (unsigned short*)wp;  wp += count_bytes;
    float* psums = (float*)wp;                  wp += 64 * sizeof(float);
    float* partials = (float*)wp;               wp += (size_t)n_rows * SPLITS * 6 * sizeof(float);
    unsigned short* lens = (unsigned short*)wp; wp += (size_t)nBlk * NBINS * sizeof(unsigned short);
    wp = (char*)(((size_t)wp + 255) & ~(size_t)255);
    unsigned short* buckets = (unsigned short*)wp;  // nBlk*NBINS*SLOTC u16 ~= 24 MB

    bucket_scatter<<<nBlk + 1, SBT, 0, stream>>>((const float4*)events, N, bpb, nBlk,
                                                 buckets, lens, pw, pb, psums);

    bucket_hist<<<n_rows, 1024, 0, stream>>>(buckets, lens, bpb, counts);

    conv_partials<<<n_rows * SPLITS, 256, 0, stream>>>(counts, gk, pw, pb, partials);

    finalize_conv<<<n_rows * FSPLIT, 256, 0, stream>>>(counts, gk, pw, pb, gw, gb,
                                                       partials, psums, out);
}

// Round 16
// 54.124 us; speedup vs baseline: 1.0208x; 1.0208x over previous
//
#include <hip/hip_runtime.h>

#define HH 128
#define WW 128
#define PP (HH * WW)     // 16384
#define NBINS 32
#define KK 5
#define PADK 2
#define EPSF 1e-5f
#define CH 8192          // events per scatter block
#define EPT 32           // events per thread (CH/256)
#define SPLITS 8
#define CPX (PP / SPLITS)  // 2048 pixels per conv block
#define SLOTC 384        // u16 entries per (block,bin) slot; mean 256, +8 sigma
#define SENT 0x4000u     // sentinel pixel id (== PP); hist slot 8192 is dead

typedef float vfloat4 __attribute__((ext_vector_type(4)));

__device__ __forceinline__ float wave_sum(float v) {
#pragma unroll
    for (int off = 32; off > 0; off >>= 1) v += __shfl_down(v, off, 64);
    return v;
}

// --------------------------------------------- phase 1: bucket the events
// Single-pass LDS bucketing; bin runs padded to 8-entry (uint4) boundaries
// with sentinels so hist can run guard-free. Extra block = param sums.
// CH=8192/24KB LDS/256 threads: measured-best config (54.1 us end-to-end).
// Probed and rejected: CH=16384 (occupancy collapse, +14us), 512-thread
// blocks (+1us), NT event loads (neutral), device-fence fusion (+120us).
__global__ __launch_bounds__(256) void bucket_scatter(
    const float4* __restrict__ ev, int N, int bpb, int nBlk,
    unsigned short* __restrict__ buckets, unsigned short* __restrict__ lens,
    const float* __restrict__ pw, const float* __restrict__ pb,
    float* __restrict__ psums) {
    int wave = threadIdx.x >> 6, lane = threadIdx.x & 63;

    if ((int)blockIdx.x == nBlk) {      // ---- param sums side-block
        __shared__ float pr[4][5];
        float s0 = 0, s1 = 0, s2 = 0, s3 = 0, s4 = 0;
        for (int i = threadIdx.x; i < PP / 4; i += 256) {
            float4 w = ((const float4*)pw)[i];
            float4 b4 = ((const float4*)pb)[i];
            s0 += w.x + w.y + w.z + w.w;
            s1 += w.x * w.x + w.y * w.y + w.z * w.z + w.w * w.w;
            s2 += b4.x + b4.y + b4.z + b4.w;
            s3 += b4.x * b4.x + b4.y * b4.y + b4.z * b4.z + b4.w * b4.w;
            s4 += w.x * b4.x + w.y * b4.y + w.z * b4.z + w.w * b4.w;
        }
        float acc[5] = {s0, s1, s2, s3, s4};
#pragma unroll
        for (int q = 0; q < 5; ++q) {
            float v = wave_sum(acc[q]);
            if (lane == 0) pr[wave][q] = v;
        }
        __syncthreads();
        if (threadIdx.x < 5)
            psums[threadIdx.x] = pr[0][threadIdx.x] + pr[1][threadIdx.x] +
                                 pr[2][threadIdx.x] + pr[3][threadIdx.x];
        return;
    }

    __shared__ unsigned int cur[NBINS];
    __shared__ unsigned short sorted[NBINS * SLOTC];   // 24 KB

    int b = blockIdx.x / bpb;
    int j = blockIdx.x - b * bpb;
    int start = j * CH;
    int nev = min(CH, N - start);
    const float4* base = ev + (size_t)b * N + start;

    if (threadIdx.x < NBINS) cur[threadIdx.x] = 0;
    __syncthreads();

#pragma unroll
    for (int k = 0; k < EPT; k++) {
        int e = threadIdx.x + k * 256;
        if (e < nev) {
            float4 q = base[e];
            int x = min(max((int)q.x, 0), HH - 1);
            int y = min(max((int)q.y, 0), WW - 1);
            float t = fminf(fmaxf(q.z, 0.0f), 1.0f);
            int bin = min((int)(t * (float)NBINS), NBINS - 1);
            unsigned int pos = atomicAdd(&cur[bin], 1u);
            if (pos < SLOTC) sorted[bin * SLOTC + pos] = (unsigned short)(x * WW + y);
        }
    }
    __syncthreads();

    // pad each bin run to an 8-entry boundary with sentinels; store padded len
    if (threadIdx.x < NBINS) {
        unsigned int len = min(cur[threadIdx.x], (unsigned int)SLOTC);
        unsigned int plen = (len + 7u) & ~7u;          // <= SLOTC (384 % 8 == 0)
        for (unsigned int i = len; i < plen; ++i)
            sorted[threadIdx.x * SLOTC + i] = (unsigned short)SENT;
        lens[(size_t)blockIdx.x * NBINS + threadIdx.x] = (unsigned short)plen;
        cur[threadIdx.x] = plen;
    }
    __syncthreads();

    // copy-out: wave w owns 8 bins; u32 writes of the padded run
    for (int i = 0; i < NBINS / 4; ++i) {
        int bin = wave * (NBINS / 4) + i;
        unsigned int nw = cur[bin] >> 1;
        unsigned int* dst = (unsigned int*)(buckets +
                            ((size_t)blockIdx.x * NBINS + bin) * SLOTC);
        const unsigned int* src = (const unsigned int*)(sorted + bin * SLOTC);
        for (unsigned int w = lane; w < nw; w += 64) dst[w] = src[w];
    }
}

// ------------------------- phase 2: per-bucket histogram (packed 16-bit)
// one block per (b,bin); guard-free uint4 slot walk, 32 KB LDS + dead slot.
__global__ __launch_bounds__(1024) void bucket_hist(
    const unsigned short* __restrict__ buckets,
    const unsigned short* __restrict__ lens, int bpb,
    unsigned short* __restrict__ counts) {
    __shared__ unsigned int hist[PP / 2 + 1];   // +1: sentinel slot (dead)
    int b = blockIdx.x >> 5;
    int bin = blockIdx.x & (NBINS - 1);
    int wave = threadIdx.x >> 6, lane = threadIdx.x & 63;

    for (int i = threadIdx.x; i < PP / 2 + 1; i += 1024) hist[i] = 0;
    __syncthreads();

    for (int j = wave; j < bpb; j += 16) {
        size_t slot = (size_t)(b * bpb + j) * NBINS + bin;
        int plen = lens[slot];                   // multiple of 8
        const uint4* src = (const uint4*)(buckets + slot * SLOTC);
        int nq = plen >> 3;
        for (int w = lane; w < nq; w += 64) {
            uint4 v = src[w];
#pragma unroll
            for (int m = 0; m < 4; ++m) {
                unsigned int pair = (&v.x)[m];
                unsigned int p0 = pair & 0xFFFFu, p1 = pair >> 16;
                atomicAdd(&hist[p0 >> 1], 1u << ((p0 & 1u) << 4));
                atomicAdd(&hist[p1 >> 1], 1u << ((p1 & 1u) << 4));
            }
        }
    }
    __syncthreads();

    unsigned int* dst = (unsigned int*)(counts + (size_t)blockIdx.x * PP);
    for (int i = threadIdx.x; i < PP / 2; i += 1024) dst[i] = hist[i];
}

// ----------------------- phase 3: conv over bins -> 6 partial sums per row
__global__ __launch_bounds__(256) void conv_partials(
    const unsigned short* __restrict__ counts, const float* __restrict__ gk,
    const float* __restrict__ pw, const float* __restrict__ pb,
    float* __restrict__ partials) {
    __shared__ float red[4][8];
    int row = blockIdx.x >> 3;          // / SPLITS
    int split = blockIdx.x & (SPLITS - 1);
    int bin = row & (NBINS - 1);
    const unsigned short* base = counts + (size_t)row * PP;
    float g0 = gk[0], g1 = gk[1], g2 = gk[2], g3 = gk[3], g4 = gk[4];

    float a0 = 0, a1 = 0, a2 = 0, a3 = 0, a4 = 0, a5 = 0;

#pragma unroll
    for (int it = 0; it < CPX / (256 * 4); ++it) {
        int p = split * CPX + (it * 256 + threadIdx.x) * 4;
        float4 c[KK];
#pragma unroll
        for (int k = 0; k < KK; ++k) {
            int bb = bin + k - PADK;
            if (bb >= 0 && bb < NBINS) {
                uint2 w = *(const uint2*)(base + (ptrdiff_t)(k - PADK) * PP + p);
                c[k] = make_float4((float)(w.x & 0xFFFFu), (float)(w.x >> 16),
                                   (float)(w.y & 0xFFFFu), (float)(w.y >> 16));
            } else {
                c[k] = make_float4(0.f, 0.f, 0.f, 0.f);
            }
        }
        float4 pw4 = *(const float4*)(pw + p);
        float4 pb4 = *(const float4*)(pb + p);

        float s0 = g0*c[0].x + g1*c[1].x + g2*c[2].x + g3*c[3].x + g4*c[4].x;
        float s1 = g0*c[0].y + g1*c[1].y + g2*c[2].y + g3*c[3].y + g4*c[4].y;
        float s2 = g0*c[0].z + g1*c[1].z + g2*c[2].z + g3*c[3].z + g4*c[4].z;
        float s3 = g0*c[0].w + g1*c[1].w + g2*c[2].w + g3*c[3].w + g4*c[4].w;

        float sv[4] = {s0, s1, s2, s3};
        float wv[4] = {pw4.x, pw4.y, pw4.z, pw4.w};
        float bv[4] = {pb4.x, pb4.y, pb4.z, pb4.w};
#pragma unroll
        for (int jj = 0; jj < 4; ++jj) {
            float s = sv[jj], w = wv[jj], bb = bv[jj];
            float sw = s * w;
            a0 += s;
            a1 += s * s;
            a2 += sw;
            a3 += sw * w;
            a4 += sw * sw;
            a5 += sw * bb;
        }
    }

    float acc[6] = {a0, a1, a2, a3, a4, a5};
    int wave = threadIdx.x >> 6, lane = threadIdx.x & 63;
#pragma unroll
    for (int q = 0; q < 6; ++q) {
        float w = wave_sum(acc[q]);
        if (lane == 0) red[wave][q] = w;
    }
    __syncthreads();
    if (threadIdx.x < 6) {
        float s = red[0][threadIdx.x] + red[1][threadIdx.x] +
                  red[2][threadIdx.x] + red[3][threadIdx.x];
        partials[(size_t)blockIdx.x * 6 + threadIdx.x] = s;
    }
}

// ------------- phase 4: recompute stats in-block + conv + both norms + out
__global__ __launch_bounds__(256) void finalize_conv(
    const unsigned short* __restrict__ counts, const float* __restrict__ gk,
    const float* __restrict__ pw, const float* __restrict__ pb,
    const float* __restrict__ gw, const float* __restrict__ gb,
    const float* __restrict__ partials, const float* __restrict__ psums,
    float* __restrict__ out) {
    __shared__ float ys[NBINS], ys2[NBINS];
    __shared__ float sstat[4];   // mu, rstd, bmu, brstd
    int row = blockIdx.x >> 3;
    int split = blockIdx.x & (SPLITS - 1);
    int bin = row & (NBINS - 1);
    int t = threadIdx.x;

    if (t < NBINS) {
        float spw = psums[0], spw2 = psums[1], spb = psums[2],
              spb2 = psums[3], spwpb = psums[4];
        int r = (row & ~(NBINS - 1)) + t;       // row t of this batch
        float S0 = 0, S1 = 0, S2 = 0, S3 = 0, S4 = 0, S5 = 0;
        for (int sp = 0; sp < SPLITS; ++sp) {
            const float* pp = partials + ((size_t)r * SPLITS + sp) * 6;
            S0 += pp[0]; S1 += pp[1]; S2 += pp[2];
            S3 += pp[3]; S4 += pp[4]; S5 += pp[5];
        }
        const float invP = 1.0f / (float)PP;
        float mu = S0 * invP;
        float var = S1 * invP - mu * mu;
        float rstd = rsqrtf(var + EPSF);
        ys[t]  = rstd * (S2 - mu * spw) + spb;
        ys2[t] = rstd * rstd * (S4 - 2.f * mu * S3 + mu * mu * spw2)
               + 2.f * rstd * (S5 - mu * spwpb) + spb2;
        if (t == bin) { sstat[0] = mu; sstat[1] = rstd; }
    }
    __syncthreads();
    if (t == 0) {
        float s = 0.f, q = 0.f;
        for (int r = 0; r < NBINS; ++r) { s += ys[r]; q += ys2[r]; }
        const float inv = 1.0f / (float)(NBINS * PP);
        float bmu = s * inv;
        float bvar = q * inv - bmu * bmu;
        sstat[2] = bmu;
        sstat[3] = rsqrtf(bvar + EPSF);
    }
    __syncthreads();
    float rmu = sstat[0], rrstd = sstat[1], bmu = sstat[2], brstd = sstat[3];

    const unsigned short* base = counts + (size_t)row * PP;
    float g0 = gk[0], g1 = gk[1], g2 = gk[2], g3 = gk[3], g4 = gk[4];

#pragma unroll
    for (int it = 0; it < CPX / (256 * 4); ++it) {
        int p = split * CPX + (it * 256 + threadIdx.x) * 4;
        float4 c[KK];
#pragma unroll
        for (int k = 0; k < KK; ++k) {
            int bb = bin + k - PADK;
            if (bb >= 0 && bb < NBINS) {
                uint2 w = *(const uint2*)(base + (ptrdiff_t)(k - PADK) * PP + p);
                c[k] = make_float4((float)(w.x & 0xFFFFu), (float)(w.x >> 16),
                                   (float)(w.y & 0xFFFFu), (float)(w.y >> 16));
            } else {
                c[k] = make_float4(0.f, 0.f, 0.f, 0.f);
            }
        }
        float4 pw4 = *(const float4*)(pw + p);
        float4 pb4 = *(const float4*)(pb + p);
        int rp = bin * PP + p;
        float4 w4 = *(const float4*)(gw + rp);
        float4 b4 = *(const float4*)(gb + rp);

        float s0 = g0*c[0].x + g1*c[1].x + g2*c[2].x + g3*c[3].x + g4*c[4].x;
        float s1 = g0*c[0].y + g1*c[1].y + g2*c[2].y + g3*c[3].y + g4*c[4].y;
        float s2 = g0*c[0].z + g1*c[1].z + g2*c[2].z + g3*c[3].z + g4*c[4].z;
        float s3 = g0*c[0].w + g1*c[1].w + g2*c[2].w + g3*c[3].w + g4*c[4].w;

        vfloat4 r;
        r.x = (((s0 - rmu) * rrstd) * pw4.x + pb4.x - bmu) * brstd * w4.x + b4.x;
        r.y = (((s1 - rmu) * rrstd) * pw4.y + pb4.y - bmu) * brstd * w4.y + b4.y;
        r.z = (((s2 - rmu) * rrstd) * pw4.z + pb4.z - bmu) * brstd * w4.z + b4.z;
        r.w = (((s3 - rmu) * rrstd) * pw4.w + pb4.w - bmu) * brstd * w4.w + b4.w;
        __builtin_nontemporal_store(r, (vfloat4*)(out + (size_t)row * PP + p));
    }
}

extern "C" void kernel_launch(void* const* d_in, const int* in_sizes, int n_in,
                              void* d_out, int out_size, void* d_ws, size_t ws_size,
                              hipStream_t stream) {
    const float* events = (const float*)d_in[0];
    const float* gk     = (const float*)d_in[2];
    const float* pw     = (const float*)d_in[3];
    const float* pb     = (const float*)d_in[4];
    const float* gw     = (const float*)d_in[5];
    const float* gb     = (const float*)d_in[6];
    float* out = (float*)d_out;

    int total_events = in_sizes[0] / 4;
    int B = out_size / (NBINS * PP);           // 8
    int N = total_events / B;                  // 1,000,000
    int n_rows = B * NBINS;                    // 256
    int bpb = (N + CH - 1) / CH;               // 123
    int nBlk = B * bpb;                        // 984

    size_t count_bytes = (size_t)out_size * sizeof(unsigned short);   // 8 MB
    char* wp = (char*)d_ws;
    unsigned short* counts = (unsigned short*)wp;  wp += count_bytes;
    float* psums = (float*)wp;                  wp += 64 * sizeof(float);
    float* partials = (float*)wp;               wp += (size_t)n_rows * SPLITS * 6 * sizeof(float);
    unsigned short* lens = (unsigned short*)wp; wp += (size_t)nBlk * NBINS * sizeof(unsigned short);
    wp = (char*)(((size_t)wp + 255) & ~(size_t)255);
    unsigned short* buckets = (unsigned short*)wp;  // nBlk*NBINS*SLOTC u16 ~= 24 MB

    bucket_scatter<<<nBlk + 1, 256, 0, stream>>>((const float4*)events, N, bpb, nBlk,
                                                 buckets, lens, pw, pb, psums);

    bucket_hist<<<n_rows, 1024, 0, stream>>>(buckets, lens, bpb, counts);

    conv_partials<<<n_rows * SPLITS, 256, 0, stream>>>(counts, gk, pw, pb, partials);

    finalize_conv<<<n_rows * SPLITS, 256, 0, stream>>>(counts, gk, pw, pb, gw, gb,
                                                       partials, psums, out);
}